// Round 2
// baseline (1058.971 us; speedup 1.0000x reference)
//
#include <hip/hip_runtime.h>

#define NN 50000
#define NE 800000
#define HD 128

typedef __attribute__((ext_vector_type(4))) float vf32x4;
typedef __attribute__((ext_vector_type(8))) __bf16 vbf16x8;
typedef __attribute__((ext_vector_type(4))) unsigned short vushort4;
typedef __attribute__((ext_vector_type(8))) unsigned short vushort8;

// ---- workspace layout (bytes) ----
constexpr size_t OFF_AGG  = 0;                       // 50000*128*4 = 25,600,000
constexpr size_t OFF_CNT  = 25600000;                // 200,000 (int counts)
constexpr size_t OFF_DX   = 25800000;                // 600,000
constexpr size_t ZBYTES   = 26400000;                // zero agg+cnt+dx
constexpr size_t OFF_OFFS = 26400000;                // 200,000 (int offsets)
constexpr size_t OFF_EID  = 26600000;                // 3,200,000 (sorted edge ids)
constexpr size_t OFF_HBF  = 29800000;                // 12,800,000 (h bf16)
constexpr size_t OFF_WE1P = 42600000;                // 65536
constexpr size_t OFF_WE2P = OFF_WE1P + 65536;        // 32768
constexpr size_t OFF_WC1P = OFF_WE2P + 32768;        // 32768
constexpr size_t OFF_WN1P = OFF_WC1P + 32768;        // 65536
constexpr size_t OFF_WN2P = OFF_WN1P + 65536;        // 32768

__device__ __forceinline__ unsigned short f2bf(float f) {
    unsigned int u = __float_as_uint(f);
    u += 0x7fffu + ((u >> 16) & 1u);
    return (unsigned short)(u >> 16);
}

__device__ __forceinline__ float silu(float v) {
    return v / (1.0f + __expf(-v));
}

// ---- histogram of edge rows ----
__global__ __launch_bounds__(256) void hist_kernel(const int* __restrict__ ei,
                                                   int* __restrict__ cnt) {
    int e = blockIdx.x * 256 + threadIdx.x;
    if (e < NE) atomicAdd(&cnt[ei[e]], 1);
}

// ---- exclusive scan of counts (single block) ----
__global__ __launch_bounds__(1024) void scan_kernel(const int* __restrict__ cnt,
                                                    int* __restrict__ offs) {
    __shared__ int sp[1024];
    int tid = threadIdx.x;
    const int CH = 49;                  // 1024*49 = 50176 >= 50000
    int base = tid * CH;
    int sum = 0;
    for (int i = 0; i < CH; i++) {
        int idx = base + i;
        if (idx < NN) sum += cnt[idx];
    }
    sp[tid] = sum;
    __syncthreads();
    for (int d = 1; d < 1024; d <<= 1) {
        int v = (tid >= d) ? sp[tid - d] : 0;
        __syncthreads();
        sp[tid] += v;
        __syncthreads();
    }
    int run = sp[tid] - sum;            // exclusive prefix of this chunk
    for (int i = 0; i < CH; i++) {
        int idx = base + i;
        if (idx < NN) {
            offs[idx] = run;
            run += cnt[idx];
        }
    }
}

// ---- scatter edge ids into row-sorted order ----
__global__ __launch_bounds__(256) void scatter_kernel(const int* __restrict__ ei,
                                                      int* __restrict__ offs,
                                                      int* __restrict__ eid) {
    int e = blockIdx.x * 256 + threadIdx.x;
    if (e < NE) {
        int r = ei[e];
        int p = atomicAdd(&offs[r], 1);
        eid[p] = e;
    }
}

// ---- convert h (f32) -> h_bf (bf16), row-major [N,128] ----
__global__ __launch_bounds__(256) void h2bf_kernel(const float* __restrict__ h,
                                                   unsigned short* __restrict__ h_bf) {
    int idx = blockIdx.x * 256 + threadIdx.x;
    vf32x4 v = ((const vf32x4*)h)[idx];
    vushort4 o;
    o[0] = f2bf(v[0]); o[1] = f2bf(v[1]); o[2] = f2bf(v[2]); o[3] = f2bf(v[3]);
    ((vushort4*)h_bf)[idx] = o;
}

// ---- pack weight [K x 128] f32 into per-lane B-fragment bf16 layout ----
__device__ __forceinline__ void pack_one(const float* __restrict__ src,
                                         unsigned short* __restrict__ dst,
                                         int local, int KB) {
    int j = local & 7;
    int lane = (local >> 3) & 63;
    int rest = local >> 9;
    int kb = rest % KB;
    int t = rest / KB;
    int srow = kb * 32 + ((lane >> 4) << 3) + j;
    int scol = t * 16 + (lane & 15);
    dst[local] = f2bf(src[srow * 128 + scol]);
}

__global__ __launch_bounds__(256) void pack_w_kernel(
    const float* __restrict__ We1, const float* __restrict__ We2,
    const float* __restrict__ Wc1, const float* __restrict__ Wn1,
    const float* __restrict__ Wn2,
    unsigned short* __restrict__ We1p, unsigned short* __restrict__ We2p,
    unsigned short* __restrict__ Wc1p, unsigned short* __restrict__ Wn1p,
    unsigned short* __restrict__ Wn2p) {
    int idx = blockIdx.x * 256 + threadIdx.x;
    if (idx < 32768)       pack_one(We1, We1p, idx, 8);
    else if (idx < 49152)  pack_one(We2, We2p, idx - 32768, 4);
    else if (idx < 65536)  pack_one(Wc1, Wc1p, idx - 49152, 4);
    else if (idx < 98304)  pack_one(Wn1, Wn1p, idx - 65536, 8);
    else                   pack_one(Wn2, Wn2p, idx - 98304, 4);
}

// ---- edge kernel: 64 sorted edges per block, 4 waves x 16 edges ----
__global__ __launch_bounds__(256) void edge_kernel(
    const float* __restrict__ x, const int* __restrict__ ei,
    const int* __restrict__ eid,
    const unsigned short* __restrict__ h_bf,
    const unsigned short* __restrict__ We1p, const unsigned short* __restrict__ We2p,
    const unsigned short* __restrict__ Wc1p,
    const float* __restrict__ We1, const float* __restrict__ be1,
    const float* __restrict__ be2, const float* __restrict__ bc1,
    const float* __restrict__ Wc2, const float* __restrict__ bc2,
    float* __restrict__ dxsum, float* __restrict__ agg) {

    __shared__ __align__(16) unsigned short s_in[64 * 264];  // reused as f32 ef (stride 132)
    __shared__ __align__(16) unsigned short s_ef[64 * 136];
    __shared__ float s_rel[64 * 4];
    __shared__ int s_row[64];
    __shared__ int s_col[64];
    __shared__ float s_gate[64];

    const int tid = threadIdx.x;
    const int ebase = blockIdx.x * 64;

    if (tid < 64) {
        int e = eid[ebase + tid];
        int r = ei[e], c = ei[NE + e];
        s_row[tid] = r;
        s_col[tid] = c;
        float d0 = x[r * 3 + 0] - x[c * 3 + 0];
        float d1 = x[r * 3 + 1] - x[c * 3 + 1];
        float d2v = x[r * 3 + 2] - x[c * 3 + 2];
        s_rel[tid * 4 + 0] = d0;
        s_rel[tid * 4 + 1] = d1;
        s_rel[tid * 4 + 2] = d2v;
        s_rel[tid * 4 + 3] = d0 * d0 + d1 * d1 + d2v * d2v;
    }
    __syncthreads();
    // stage [h[row] | h[col]] bf16 rows: 128 rows x 16 chunks of 16B
#pragma unroll
    for (int i = 0; i < 8; i++) {
        int flat = i * 256 + tid;
        int rowid = flat >> 4;
        int seg = flat & 15;
        int el = rowid >> 1;
        int node = (rowid & 1) ? s_col[el] : s_row[el];
        vushort8 v = *(const vushort8*)(h_bf + node * 128 + seg * 8);
        *(vushort8*)(&s_in[el * 264 + (rowid & 1) * 128 + seg * 8]) = v;
    }
    __syncthreads();

    const int wave = tid >> 6, lane = tid & 63;
    const int li = lane & 15, grp = lane >> 4;
    const vf32x4 vzero = {0.f, 0.f, 0.f, 0.f};

    // ---- layer 1: [64,256] @ We1[256,128] ----
    vf32x4 acc[8];
#pragma unroll
    for (int t = 0; t < 8; t++) acc[t] = vzero;
    {
        const unsigned short* arow = s_in + (wave * 16 + li) * 264 + grp * 8;
#pragma unroll
        for (int kb = 0; kb < 8; kb++) {
            vbf16x8 a = *(const vbf16x8*)(arow + kb * 32);
#pragma unroll
            for (int t = 0; t < 8; t++) {
                vbf16x8 b = *(const vbf16x8*)(We1p + ((t * 8 + kb) * 64 + lane) * 8);
                acc[t] = __builtin_amdgcn_mfma_f32_16x16x32_bf16(a, b, acc[t], 0, 0, 0);
            }
        }
    }
    float d2[4];
#pragma unroll
    for (int r = 0; r < 4; r++) d2[r] = s_rel[(wave * 16 + grp * 4 + r) * 4 + 3];
#pragma unroll
    for (int t = 0; t < 8; t++) {
        int col = t * 16 + li;
        float b1 = be1[col], wl = We1[256 * 128 + col];
#pragma unroll
        for (int r = 0; r < 4; r++) {
            float v = silu(acc[t][r] + b1 + d2[r] * wl);
            s_ef[(wave * 16 + grp * 4 + r) * 136 + col] = f2bf(v);
        }
    }
    __syncthreads();

    // ---- layer 2: ef1 @ We2[128,128] ----
#pragma unroll
    for (int t = 0; t < 8; t++) acc[t] = vzero;
    {
        const unsigned short* arow = s_ef + (wave * 16 + li) * 136 + grp * 8;
#pragma unroll
        for (int kb = 0; kb < 4; kb++) {
            vbf16x8 a = *(const vbf16x8*)(arow + kb * 32);
#pragma unroll
            for (int t = 0; t < 8; t++) {
                vbf16x8 b = *(const vbf16x8*)(We2p + ((t * 4 + kb) * 64 + lane) * 8);
                acc[t] = __builtin_amdgcn_mfma_f32_16x16x32_bf16(a, b, acc[t], 0, 0, 0);
            }
        }
    }
    float ef_reg[8][4];
#pragma unroll
    for (int t = 0; t < 8; t++) {
        float b2 = be2[t * 16 + li];
#pragma unroll
        for (int r = 0; r < 4; r++) ef_reg[t][r] = silu(acc[t][r] + b2);
    }
    __syncthreads();
#pragma unroll
    for (int t = 0; t < 8; t++) {
        int col = t * 16 + li;
#pragma unroll
        for (int r = 0; r < 4; r++)
            s_ef[(wave * 16 + grp * 4 + r) * 136 + col] = f2bf(ef_reg[t][r]);
    }
    __syncthreads();

    // ---- gate: silu(ef @ Wc1 + bc1) . Wc2 + bc2 ----
#pragma unroll
    for (int t = 0; t < 8; t++) acc[t] = vzero;
    {
        const unsigned short* arow = s_ef + (wave * 16 + li) * 136 + grp * 8;
#pragma unroll
        for (int kb = 0; kb < 4; kb++) {
            vbf16x8 a = *(const vbf16x8*)(arow + kb * 32);
#pragma unroll
            for (int t = 0; t < 8; t++) {
                vbf16x8 b = *(const vbf16x8*)(Wc1p + ((t * 4 + kb) * 64 + lane) * 8);
                acc[t] = __builtin_amdgcn_mfma_f32_16x16x32_bf16(a, b, acc[t], 0, 0, 0);
            }
        }
    }
    float gp[4] = {0.f, 0.f, 0.f, 0.f};
#pragma unroll
    for (int t = 0; t < 8; t++) {
        int col = t * 16 + li;
        float bc = bc1[col], w2 = Wc2[col];
#pragma unroll
        for (int r = 0; r < 4; r++) gp[r] += silu(acc[t][r] + bc) * w2;
    }
#pragma unroll
    for (int r = 0; r < 4; r++) {
#pragma unroll
        for (int d = 1; d < 16; d <<= 1) gp[r] += __shfl_xor(gp[r], d, 16);
        gp[r] += bc2[0];
    }

    // ---- store f32 ef into s_in-as-f32 (stride 132: 2-way bank alias = free) ----
    float* s_f32 = (float*)s_in;
#pragma unroll
    for (int t = 0; t < 8; t++) {
        int col = t * 16 + li;
#pragma unroll
        for (int r = 0; r < 4; r++)
            s_f32[(wave * 16 + grp * 4 + r) * 132 + col] = ef_reg[t][r];
    }
    if (li == 0) {
#pragma unroll
        for (int r = 0; r < 4; r++) s_gate[wave * 16 + grp * 4 + r] = gp[r];
    }
    __syncthreads();

    // ---- segmented reduction over sorted rows; few atomics per block ----
    {
        int colh = tid >> 1, half = tid & 1;
        int e0 = half * 32;
        float a2 = 0.f;
        int prow = s_row[e0];
        for (int e = e0; e < e0 + 32; e++) {
            int rw = s_row[e];
            if (rw != prow) {
                atomicAdd(&agg[prow * 128 + colh], a2);
                a2 = 0.f;
                prow = rw;
            }
            a2 += s_f32[e * 132 + colh];
        }
        atomicAdd(&agg[prow * 128 + colh], a2);
    }
    if (tid < 6) {
        int comp = tid % 3, hf = tid / 3;
        int e0 = hf * 32;
        float a2 = 0.f;
        int prow = s_row[e0];
        for (int e = e0; e < e0 + 32; e++) {
            int rw = s_row[e];
            if (rw != prow) {
                atomicAdd(&dxsum[prow * 3 + comp], a2);
                a2 = 0.f;
                prow = rw;
            }
            a2 += s_rel[e * 4 + comp] * s_gate[e];
        }
        atomicAdd(&dxsum[prow * 3 + comp], a2);
    }
}

// ---- node kernel: 64 nodes per block ----
__global__ __launch_bounds__(256) void node_kernel(
    const float* __restrict__ x, const float* __restrict__ h32,
    const unsigned short* __restrict__ h_bf,
    const int* __restrict__ counts, const float* __restrict__ dxsum,
    const float* __restrict__ agg,
    const unsigned short* __restrict__ Wn1p, const unsigned short* __restrict__ Wn2p,
    const float* __restrict__ bn1, const float* __restrict__ bn2,
    const float* __restrict__ gamma, const float* __restrict__ beta,
    float* __restrict__ out) {

    __shared__ __align__(16) unsigned short s_in[64 * 264];
    __shared__ __align__(16) unsigned short s_ef[64 * 136];

    const int tid = threadIdx.x;
    const int nbase = blockIdx.x * 64;

    // x_out = x + dx/cnt
    {
        int idx = blockIdx.x * 192 + tid;
        if (tid < 192 && idx < NN * 3) {
            int node = idx / 3;
            float cnt = fmaxf((float)counts[node], 1.0f);
            out[idx] = x[idx] + dxsum[idx] / cnt;
        }
    }
    // stage h (bf16)
#pragma unroll
    for (int i = 0; i < 4; i++) {
        int flat = i * 256 + tid;
        int row = flat >> 4, seg = flat & 15;
        int node = nbase + row;
        if (node >= NN) node = NN - 1;
        vushort8 v = *(const vushort8*)(h_bf + node * 128 + seg * 8);
        *(vushort8*)(&s_in[row * 264 + seg * 8]) = v;
    }
    // stage agg/cnt (f32 -> bf16)
#pragma unroll
    for (int i = 0; i < 8; i++) {
        int flat = i * 256 + tid;
        int row = flat >> 5, q = flat & 31;
        int node = nbase + row;
        if (node >= NN) node = NN - 1;
        float inv = 1.0f / fmaxf((float)counts[node], 1.0f);
        vf32x4 v = *(const vf32x4*)(agg + node * 128 + q * 4);
        vushort4 o;
        o[0] = f2bf(v[0] * inv); o[1] = f2bf(v[1] * inv);
        o[2] = f2bf(v[2] * inv); o[3] = f2bf(v[3] * inv);
        *(vushort4*)(&s_in[row * 264 + 128 + q * 4]) = o;
    }
    __syncthreads();

    const int wave = tid >> 6, lane = tid & 63;
    const int li = lane & 15, grp = lane >> 4;
    const vf32x4 vzero = {0.f, 0.f, 0.f, 0.f};

    // GEMM1: [64,256] @ Wn1[256,128], silu
    vf32x4 acc[8];
#pragma unroll
    for (int t = 0; t < 8; t++) acc[t] = vzero;
    {
        const unsigned short* arow = s_in + (wave * 16 + li) * 264 + grp * 8;
#pragma unroll
        for (int kb = 0; kb < 8; kb++) {
            vbf16x8 a = *(const vbf16x8*)(arow + kb * 32);
#pragma unroll
            for (int t = 0; t < 8; t++) {
                vbf16x8 b = *(const vbf16x8*)(Wn1p + ((t * 8 + kb) * 64 + lane) * 8);
                acc[t] = __builtin_amdgcn_mfma_f32_16x16x32_bf16(a, b, acc[t], 0, 0, 0);
            }
        }
    }
#pragma unroll
    for (int t = 0; t < 8; t++) {
        int col = t * 16 + li;
        float b1 = bn1[col];
#pragma unroll
        for (int r = 0; r < 4; r++) {
            float v = silu(acc[t][r] + b1);
            s_ef[(wave * 16 + grp * 4 + r) * 136 + col] = f2bf(v);
        }
    }
    __syncthreads();

    // GEMM2: @ Wn2[128,128] + bn2 + h, then LN + silu
#pragma unroll
    for (int t = 0; t < 8; t++) acc[t] = vzero;
    {
        const unsigned short* arow = s_ef + (wave * 16 + li) * 136 + grp * 8;
#pragma unroll
        for (int kb = 0; kb < 4; kb++) {
            vbf16x8 a = *(const vbf16x8*)(arow + kb * 32);
#pragma unroll
            for (int t = 0; t < 8; t++) {
                vbf16x8 b = *(const vbf16x8*)(Wn2p + ((t * 4 + kb) * 64 + lane) * 8);
                acc[t] = __builtin_amdgcn_mfma_f32_16x16x32_bf16(a, b, acc[t], 0, 0, 0);
            }
        }
    }
    float h2v[8][4];
    float sum[4] = {0.f, 0.f, 0.f, 0.f}, sq[4] = {0.f, 0.f, 0.f, 0.f};
#pragma unroll
    for (int t = 0; t < 8; t++) {
        int col = t * 16 + li;
        float b2 = bn2[col];
#pragma unroll
        for (int r = 0; r < 4; r++) {
            int node = nbase + wave * 16 + grp * 4 + r;
            int nc = node < NN ? node : NN - 1;
            float v = acc[t][r] + b2 + h32[nc * 128 + col];
            h2v[t][r] = v;
            sum[r] += v;
            sq[r] += v * v;
        }
    }
    float mu[4], rstd[4];
#pragma unroll
    for (int r = 0; r < 4; r++) {
#pragma unroll
        for (int d = 1; d < 16; d <<= 1) {
            sum[r] += __shfl_xor(sum[r], d, 16);
            sq[r] += __shfl_xor(sq[r], d, 16);
        }
        mu[r] = sum[r] * (1.0f / 128.0f);
        float var = sq[r] * (1.0f / 128.0f) - mu[r] * mu[r];
        rstd[r] = rsqrtf(var + 1e-5f);
    }
#pragma unroll
    for (int t = 0; t < 8; t++) {
        int col = t * 16 + li;
        float g = gamma[col], bt = beta[col];
#pragma unroll
        for (int r = 0; r < 4; r++) {
            int node = nbase + wave * 16 + grp * 4 + r;
            if (node < NN) {
                float vn = (h2v[t][r] - mu[r]) * rstd[r] * g + bt;
                out[NN * 3 + node * 128 + col] = silu(vn);
            }
        }
    }
}

extern "C" void kernel_launch(void* const* d_in, const int* in_sizes, int n_in,
                              void* d_out, int out_size, void* d_ws, size_t ws_size,
                              hipStream_t stream) {
    const float* x     = (const float*)d_in[0];
    const float* h     = (const float*)d_in[1];
    const int* ei      = (const int*)d_in[2];
    const float* We1   = (const float*)d_in[3];
    const float* be1   = (const float*)d_in[4];
    const float* We2   = (const float*)d_in[5];
    const float* be2   = (const float*)d_in[6];
    const float* Wc1   = (const float*)d_in[7];
    const float* bc1   = (const float*)d_in[8];
    const float* Wc2   = (const float*)d_in[9];
    const float* bc2   = (const float*)d_in[10];
    const float* Wn1   = (const float*)d_in[11];
    const float* bn1   = (const float*)d_in[12];
    const float* Wn2   = (const float*)d_in[13];
    const float* bn2   = (const float*)d_in[14];
    const float* gamma = (const float*)d_in[15];
    const float* beta  = (const float*)d_in[16];
    float* out = (float*)d_out;

    char* ws = (char*)d_ws;
    float* agg            = (float*)(ws + OFF_AGG);
    int* cnt              = (int*)(ws + OFF_CNT);
    float* dxsum          = (float*)(ws + OFF_DX);
    int* offs             = (int*)(ws + OFF_OFFS);
    int* eid              = (int*)(ws + OFF_EID);
    unsigned short* h_bf  = (unsigned short*)(ws + OFF_HBF);
    unsigned short* We1p  = (unsigned short*)(ws + OFF_WE1P);
    unsigned short* We2p  = (unsigned short*)(ws + OFF_WE2P);
    unsigned short* Wc1p  = (unsigned short*)(ws + OFF_WC1P);
    unsigned short* Wn1p  = (unsigned short*)(ws + OFF_WN1P);
    unsigned short* Wn2p  = (unsigned short*)(ws + OFF_WN2P);

    hipMemsetAsync(ws, 0, ZBYTES, stream);
    hist_kernel<<<NE / 256, 256, 0, stream>>>(ei, cnt);
    h2bf_kernel<<<NN * 128 / 4 / 256, 256, 0, stream>>>(h, h_bf);
    pack_w_kernel<<<114688 / 256, 256, 0, stream>>>(We1, We2, Wc1, Wn1, Wn2,
                                                    We1p, We2p, Wc1p, Wn1p, Wn2p);
    scan_kernel<<<1, 1024, 0, stream>>>(cnt, offs);
    scatter_kernel<<<NE / 256, 256, 0, stream>>>(ei, offs, eid);
    edge_kernel<<<NE / 64, 256, 0, stream>>>(x, ei, eid, h_bf, We1p, We2p, Wc1p,
                                             We1, be1, be2, bc1, Wc2, bc2,
                                             dxsum, agg);
    node_kernel<<<(NN + 63) / 64, 256, 0, stream>>>(x, h, h_bf, cnt, dxsum, agg,
                                                    Wn1p, Wn2p, bn1, bn2, gamma, beta, out);
}

// Round 3
// 618.001 us; speedup vs baseline: 1.7135x; 1.7135x over previous
//
#include <hip/hip_runtime.h>

#define NN 50000
#define NE 800000
#define HD 128

typedef __attribute__((ext_vector_type(4))) float vf32x4;
typedef __attribute__((ext_vector_type(8))) __bf16 vbf16x8;
typedef __attribute__((ext_vector_type(4))) unsigned short vushort4;
typedef __attribute__((ext_vector_type(8))) unsigned short vushort8;

// ---- workspace layout (bytes) ----
constexpr size_t OFF_AGG  = 0;                       // 50000*128*4 = 25,600,000
constexpr size_t OFF_CNT  = 25600000;                // 200,000 (float counts)
constexpr size_t OFF_DX   = 25800000;                // 600,000
constexpr size_t ZBYTES   = 26400000;                // zero agg+cnt+dx
constexpr size_t OFF_HBF  = 26400000;                // 12,800,000 (h bf16)
constexpr size_t OFF_WE1P = 39200000;                // 65536
constexpr size_t OFF_WE2P = OFF_WE1P + 65536;        // 32768
constexpr size_t OFF_WC1P = OFF_WE2P + 32768;        // 32768
constexpr size_t OFF_WN1P = OFF_WC1P + 32768;        // 65536
constexpr size_t OFF_WN2P = OFF_WN1P + 65536;        // 32768

__device__ __forceinline__ unsigned short f2bf(float f) {
    unsigned int u = __float_as_uint(f);
    u += 0x7fffu + ((u >> 16) & 1u);
    return (unsigned short)(u >> 16);
}

__device__ __forceinline__ float silu(float v) {
    return __fdividef(v, 1.0f + __expf(-v));
}

// ---- convert h (f32) -> h_bf (bf16), row-major [N,128] ----
__global__ __launch_bounds__(256) void h2bf_kernel(const float* __restrict__ h,
                                                   unsigned short* __restrict__ h_bf) {
    int idx = blockIdx.x * 256 + threadIdx.x;
    vf32x4 v = ((const vf32x4*)h)[idx];
    vushort4 o;
    o[0] = f2bf(v[0]); o[1] = f2bf(v[1]); o[2] = f2bf(v[2]); o[3] = f2bf(v[3]);
    ((vushort4*)h_bf)[idx] = o;
}

// ---- pack weight [K x 128] f32 into per-lane B-fragment bf16 layout ----
__device__ __forceinline__ void pack_one(const float* __restrict__ src,
                                         unsigned short* __restrict__ dst,
                                         int local, int KB) {
    int j = local & 7;
    int lane = (local >> 3) & 63;
    int rest = local >> 9;
    int kb = rest % KB;
    int t = rest / KB;
    int srow = kb * 32 + ((lane >> 4) << 3) + j;
    int scol = t * 16 + (lane & 15);
    dst[local] = f2bf(src[srow * 128 + scol]);
}

__global__ __launch_bounds__(256) void pack_w_kernel(
    const float* __restrict__ We1, const float* __restrict__ We2,
    const float* __restrict__ Wc1, const float* __restrict__ Wn1,
    const float* __restrict__ Wn2,
    unsigned short* __restrict__ We1p, unsigned short* __restrict__ We2p,
    unsigned short* __restrict__ Wc1p, unsigned short* __restrict__ Wn1p,
    unsigned short* __restrict__ Wn2p) {
    int idx = blockIdx.x * 256 + threadIdx.x;
    if (idx < 32768)       pack_one(We1, We1p, idx, 8);
    else if (idx < 49152)  pack_one(We2, We2p, idx - 32768, 4);
    else if (idx < 65536)  pack_one(Wc1, Wc1p, idx - 49152, 4);
    else if (idx < 98304)  pack_one(Wn1, Wn1p, idx - 65536, 8);
    else                   pack_one(Wn2, Wn2p, idx - 98304, 4);
}

// ---- edge kernel: 64 edges per block, 4 waves x 16 edges ----
// A-fragments loaded DIRECTLY from global h_bf (no LDS staging) -> 19KB LDS.
__global__ __launch_bounds__(256, 4) void edge_kernel(
    const float* __restrict__ x, const int* __restrict__ ei,
    const unsigned short* __restrict__ h_bf,
    const unsigned short* __restrict__ We1p, const unsigned short* __restrict__ We2p,
    const unsigned short* __restrict__ Wc1p,
    const float* __restrict__ We1, const float* __restrict__ be1,
    const float* __restrict__ be2, const float* __restrict__ bc1,
    const float* __restrict__ Wc2, const float* __restrict__ bc2,
    float* __restrict__ counts, float* __restrict__ dxsum, float* __restrict__ agg) {

    __shared__ __align__(16) unsigned short s_ef[64 * 136];
    __shared__ float s_rel[64 * 4];
    __shared__ int s_row[64];
    __shared__ int s_col[64];

    const int tid = threadIdx.x;
    const int ebase = blockIdx.x * 64;

    if (tid < 64) {
        int e = ebase + tid;
        int r = ei[e], c = ei[NE + e];
        s_row[tid] = r;
        s_col[tid] = c;
        float d0 = x[r * 3 + 0] - x[c * 3 + 0];
        float d1 = x[r * 3 + 1] - x[c * 3 + 1];
        float d2v = x[r * 3 + 2] - x[c * 3 + 2];
        s_rel[tid * 4 + 0] = d0;
        s_rel[tid * 4 + 1] = d1;
        s_rel[tid * 4 + 2] = d2v;
        s_rel[tid * 4 + 3] = d0 * d0 + d1 * d1 + d2v * d2v;
    }
    __syncthreads();

    const int wave = tid >> 6, lane = tid & 63;
    const int li = lane & 15, grp = lane >> 4;
    const int el = wave * 16 + li;
    const vf32x4 vzero = {0.f, 0.f, 0.f, 0.f};

    // ---- direct global A-fragment loads: [h[row] | h[col]] ----
    vbf16x8 af[8];
    {
        const unsigned short* pr = h_bf + (size_t)s_row[el] * 128 + grp * 8;
        const unsigned short* pc = h_bf + (size_t)s_col[el] * 128 + grp * 8;
#pragma unroll
        for (int kb = 0; kb < 4; kb++) af[kb] = *(const vbf16x8*)(pr + kb * 32);
#pragma unroll
        for (int kb = 0; kb < 4; kb++) af[4 + kb] = *(const vbf16x8*)(pc + kb * 32);
    }

    // ---- layer 1: [64,256] @ We1[256,128] ----
    vf32x4 acc[8];
#pragma unroll
    for (int t = 0; t < 8; t++) acc[t] = vzero;
#pragma unroll
    for (int kb = 0; kb < 8; kb++) {
#pragma unroll
        for (int t = 0; t < 8; t++) {
            vbf16x8 b = *(const vbf16x8*)(We1p + ((t * 8 + kb) * 64 + lane) * 8);
            acc[t] = __builtin_amdgcn_mfma_f32_16x16x32_bf16(af[kb], b, acc[t], 0, 0, 0);
        }
    }
    float d2[4];
#pragma unroll
    for (int r = 0; r < 4; r++) d2[r] = s_rel[(wave * 16 + grp * 4 + r) * 4 + 3];
#pragma unroll
    for (int t = 0; t < 8; t++) {
        int col = t * 16 + li;
        float b1 = be1[col], wl = We1[256 * 128 + col];
#pragma unroll
        for (int r = 0; r < 4; r++) {
            float v = silu(acc[t][r] + b1 + d2[r] * wl);
            s_ef[(wave * 16 + grp * 4 + r) * 136 + col] = f2bf(v);
        }
    }
    __syncthreads();

    // ---- layer 2: ef1 @ We2[128,128] ----
#pragma unroll
    for (int t = 0; t < 8; t++) acc[t] = vzero;
    {
        const unsigned short* arow = s_ef + (wave * 16 + li) * 136 + grp * 8;
#pragma unroll
        for (int kb = 0; kb < 4; kb++) {
            vbf16x8 a = *(const vbf16x8*)(arow + kb * 32);
#pragma unroll
            for (int t = 0; t < 8; t++) {
                vbf16x8 b = *(const vbf16x8*)(We2p + ((t * 4 + kb) * 64 + lane) * 8);
                acc[t] = __builtin_amdgcn_mfma_f32_16x16x32_bf16(a, b, acc[t], 0, 0, 0);
            }
        }
    }
    float ef_reg[8][4];
#pragma unroll
    for (int t = 0; t < 8; t++) {
        float b2 = be2[t * 16 + li];
#pragma unroll
        for (int r = 0; r < 4; r++) ef_reg[t][r] = silu(acc[t][r] + b2);
    }
    __syncthreads();
#pragma unroll
    for (int t = 0; t < 8; t++) {
        int col = t * 16 + li;
#pragma unroll
        for (int r = 0; r < 4; r++)
            s_ef[(wave * 16 + grp * 4 + r) * 136 + col] = f2bf(ef_reg[t][r]);
    }
    __syncthreads();

    // ---- gate: silu(ef @ Wc1 + bc1) . Wc2 + bc2 ----
#pragma unroll
    for (int t = 0; t < 8; t++) acc[t] = vzero;
    {
        const unsigned short* arow = s_ef + (wave * 16 + li) * 136 + grp * 8;
#pragma unroll
        for (int kb = 0; kb < 4; kb++) {
            vbf16x8 a = *(const vbf16x8*)(arow + kb * 32);
#pragma unroll
            for (int t = 0; t < 8; t++) {
                vbf16x8 b = *(const vbf16x8*)(Wc1p + ((t * 4 + kb) * 64 + lane) * 8);
                acc[t] = __builtin_amdgcn_mfma_f32_16x16x32_bf16(a, b, acc[t], 0, 0, 0);
            }
        }
    }
    float gp[4] = {0.f, 0.f, 0.f, 0.f};
#pragma unroll
    for (int t = 0; t < 8; t++) {
        int col = t * 16 + li;
        float bc = bc1[col], w2 = Wc2[col];
#pragma unroll
        for (int r = 0; r < 4; r++) gp[r] += silu(acc[t][r] + bc) * w2;
    }
#pragma unroll
    for (int r = 0; r < 4; r++) {
#pragma unroll
        for (int d = 1; d < 16; d <<= 1) gp[r] += __shfl_xor(gp[r], d, 16);
        gp[r] += bc2[0];
    }

    // ---- scatter (atomics, from registers) ----
#pragma unroll
    for (int r = 0; r < 4; r++) {
        int e2 = wave * 16 + grp * 4 + r;
        int node = s_row[e2];
#pragma unroll
        for (int t = 0; t < 8; t++)
            atomicAdd(&agg[(size_t)node * 128 + t * 16 + li], ef_reg[t][r]);
        if (li < 3)
            atomicAdd(&dxsum[node * 3 + li], s_rel[e2 * 4 + li] * gp[r]);
        else if (li == 3)
            atomicAdd(&counts[node], 1.0f);
    }
}

// ---- node kernel: 64 nodes per block ----
__global__ __launch_bounds__(256, 4) void node_kernel(
    const float* __restrict__ x, const float* __restrict__ h32,
    const unsigned short* __restrict__ h_bf,
    const float* __restrict__ counts, const float* __restrict__ dxsum,
    const float* __restrict__ agg,
    const unsigned short* __restrict__ Wn1p, const unsigned short* __restrict__ Wn2p,
    const float* __restrict__ bn1, const float* __restrict__ bn2,
    const float* __restrict__ gamma, const float* __restrict__ beta,
    float* __restrict__ out) {

    __shared__ __align__(16) unsigned short s_agg[64 * 136];
    __shared__ __align__(16) unsigned short s_ef[64 * 136];

    const int tid = threadIdx.x;
    const int nbase = blockIdx.x * 64;

    // x_out = x + dx/cnt
    {
        int idx = blockIdx.x * 192 + tid;
        if (tid < 192 && idx < NN * 3) {
            int node = idx / 3;
            float cnt = fmaxf(counts[node], 1.0f);
            out[idx] = x[idx] + dxsum[idx] / cnt;
        }
    }
    // stage agg (f32 -> bf16, divided by count)
#pragma unroll
    for (int i = 0; i < 8; i++) {
        int flat = i * 256 + tid;
        int row = flat >> 5, q = flat & 31;
        int node = nbase + row;
        if (node >= NN) node = NN - 1;
        float inv = 1.0f / fmaxf(counts[node], 1.0f);
        vf32x4 v = *(const vf32x4*)(agg + (size_t)node * 128 + q * 4);
        vushort4 o;
        o[0] = f2bf(v[0] * inv); o[1] = f2bf(v[1] * inv);
        o[2] = f2bf(v[2] * inv); o[3] = f2bf(v[3] * inv);
        *(vushort4*)(&s_agg[row * 136 + q * 4]) = o;
    }
    __syncthreads();

    const int wave = tid >> 6, lane = tid & 63;
    const int li = lane & 15, grp = lane >> 4;
    const vf32x4 vzero = {0.f, 0.f, 0.f, 0.f};

    int mynode = nbase + wave * 16 + li;
    if (mynode >= NN) mynode = NN - 1;

    // GEMM1: [64,256] @ Wn1[256,128] ; A = [h (direct global) | agg (LDS)]
    vbf16x8 af[8];
    {
        const unsigned short* ph = h_bf + (size_t)mynode * 128 + grp * 8;
#pragma unroll
        for (int kb = 0; kb < 4; kb++) af[kb] = *(const vbf16x8*)(ph + kb * 32);
        const unsigned short* pa = s_agg + (wave * 16 + li) * 136 + grp * 8;
#pragma unroll
        for (int kb = 0; kb < 4; kb++) af[4 + kb] = *(const vbf16x8*)(pa + kb * 32);
    }
    vf32x4 acc[8];
#pragma unroll
    for (int t = 0; t < 8; t++) acc[t] = vzero;
#pragma unroll
    for (int kb = 0; kb < 8; kb++) {
#pragma unroll
        for (int t = 0; t < 8; t++) {
            vbf16x8 b = *(const vbf16x8*)(Wn1p + ((t * 8 + kb) * 64 + lane) * 8);
            acc[t] = __builtin_amdgcn_mfma_f32_16x16x32_bf16(af[kb], b, acc[t], 0, 0, 0);
        }
    }
#pragma unroll
    for (int t = 0; t < 8; t++) {
        int col = t * 16 + li;
        float b1 = bn1[col];
#pragma unroll
        for (int r = 0; r < 4; r++) {
            float v = silu(acc[t][r] + b1);
            s_ef[(wave * 16 + grp * 4 + r) * 136 + col] = f2bf(v);
        }
    }
    __syncthreads();

    // GEMM2: @ Wn2[128,128] + bn2 + h, then LN + silu
#pragma unroll
    for (int t = 0; t < 8; t++) acc[t] = vzero;
    {
        const unsigned short* arow = s_ef + (wave * 16 + li) * 136 + grp * 8;
#pragma unroll
        for (int kb = 0; kb < 4; kb++) {
            vbf16x8 a = *(const vbf16x8*)(arow + kb * 32);
#pragma unroll
            for (int t = 0; t < 8; t++) {
                vbf16x8 b = *(const vbf16x8*)(Wn2p + ((t * 4 + kb) * 64 + lane) * 8);
                acc[t] = __builtin_amdgcn_mfma_f32_16x16x32_bf16(a, b, acc[t], 0, 0, 0);
            }
        }
    }
    float h2v[8][4];
    float sum[4] = {0.f, 0.f, 0.f, 0.f}, sq[4] = {0.f, 0.f, 0.f, 0.f};
#pragma unroll
    for (int t = 0; t < 8; t++) {
        int col = t * 16 + li;
        float b2 = bn2[col];
#pragma unroll
        for (int r = 0; r < 4; r++) {
            int node = nbase + wave * 16 + grp * 4 + r;
            int nc = node < NN ? node : NN - 1;
            float v = acc[t][r] + b2 + h32[(size_t)nc * 128 + col];
            h2v[t][r] = v;
            sum[r] += v;
            sq[r] += v * v;
        }
    }
    float mu[4], rstd[4];
#pragma unroll
    for (int r = 0; r < 4; r++) {
#pragma unroll
        for (int d = 1; d < 16; d <<= 1) {
            sum[r] += __shfl_xor(sum[r], d, 16);
            sq[r] += __shfl_xor(sq[r], d, 16);
        }
        mu[r] = sum[r] * (1.0f / 128.0f);
        float var = sq[r] * (1.0f / 128.0f) - mu[r] * mu[r];
        rstd[r] = rsqrtf(var + 1e-5f);
    }
#pragma unroll
    for (int t = 0; t < 8; t++) {
        int col = t * 16 + li;
        float g = gamma[col], bt = beta[col];
#pragma unroll
        for (int r = 0; r < 4; r++) {
            int node = nbase + wave * 16 + grp * 4 + r;
            if (node < NN) {
                float vn = (h2v[t][r] - mu[r]) * rstd[r] * g + bt;
                out[NN * 3 + (size_t)node * 128 + col] = silu(vn);
            }
        }
    }
}

extern "C" void kernel_launch(void* const* d_in, const int* in_sizes, int n_in,
                              void* d_out, int out_size, void* d_ws, size_t ws_size,
                              hipStream_t stream) {
    const float* x     = (const float*)d_in[0];
    const float* h     = (const float*)d_in[1];
    const int* ei      = (const int*)d_in[2];
    const float* We1   = (const float*)d_in[3];
    const float* be1   = (const float*)d_in[4];
    const float* We2   = (const float*)d_in[5];
    const float* be2   = (const float*)d_in[6];
    const float* Wc1   = (const float*)d_in[7];
    const float* bc1   = (const float*)d_in[8];
    const float* Wc2   = (const float*)d_in[9];
    const float* bc2   = (const float*)d_in[10];
    const float* Wn1   = (const float*)d_in[11];
    const float* bn1   = (const float*)d_in[12];
    const float* Wn2   = (const float*)d_in[13];
    const float* bn2   = (const float*)d_in[14];
    const float* gamma = (const float*)d_in[15];
    const float* beta  = (const float*)d_in[16];
    float* out = (float*)d_out;

    char* ws = (char*)d_ws;
    float* agg            = (float*)(ws + OFF_AGG);
    float* counts         = (float*)(ws + OFF_CNT);
    float* dxsum          = (float*)(ws + OFF_DX);
    unsigned short* h_bf  = (unsigned short*)(ws + OFF_HBF);
    unsigned short* We1p  = (unsigned short*)(ws + OFF_WE1P);
    unsigned short* We2p  = (unsigned short*)(ws + OFF_WE2P);
    unsigned short* Wc1p  = (unsigned short*)(ws + OFF_WC1P);
    unsigned short* Wn1p  = (unsigned short*)(ws + OFF_WN1P);
    unsigned short* Wn2p  = (unsigned short*)(ws + OFF_WN2P);

    hipMemsetAsync(ws, 0, ZBYTES, stream);
    h2bf_kernel<<<NN * 128 / 4 / 256, 256, 0, stream>>>(h, h_bf);
    pack_w_kernel<<<114688 / 256, 256, 0, stream>>>(We1, We2, Wc1, Wn1, Wn2,
                                                    We1p, We2p, Wc1p, Wn1p, Wn2p);
    edge_kernel<<<NE / 64, 256, 0, stream>>>(x, ei, h_bf, We1p, We2p, Wc1p,
                                             We1, be1, be2, bc1, Wc2, bc2,
                                             counts, dxsum, agg);
    node_kernel<<<(NN + 63) / 64, 256, 0, stream>>>(x, h, h_bf, counts, dxsum, agg,
                                                    Wn1p, Wn2p, bn1, bn2, gamma, beta, out);
}